// Round 5
// baseline (922.520 us; speedup 1.0000x reference)
//
#include <hip/hip_runtime.h>
#include <hip/hip_bf16.h>

// Single-head causal attention, B=4096, T=64, C=128, H=64.
// Grid 2048 x 256thr; each block does NB=2 batches with cross-batch x prefetch.
// Wave w owns query rows [16w,16w+16). All matmuls bf16 MFMA 16x16x32,
// operand-swapped so q/k/P tiles land row-packed and out stores are float4.
// Key fix vs R3: explicit batched loads + big reg budget to restore MLP
// (R3: VGPR=40 serialized ~76 loads/thread -> 100us latency-bound).

typedef __bf16 bf16_t;
typedef __bf16 bf16x8 __attribute__((ext_vector_type(8)));
typedef __bf16 bf16x4 __attribute__((ext_vector_type(4)));
typedef float  f32x4  __attribute__((ext_vector_type(4)));

#define K_OFF   0        // K [s][h]  64x64 bf16, rowstride 128 B, swizzled
#define VT_OFF  8192     // VT [h][s] 64x64 bf16
#define QS_OFF  16384    // per-wave scratch (q then P): w*2048, 16x64 bf16
#define LDS_BYTES 24576
#define NB 2

__device__ __forceinline__ int swz(int off, int row) { return off ^ ((row & 7) << 4); }

__device__ __forceinline__ bf16x8 pack8(float4 a, float4 b) {
    bf16x8 r;
    r[0] = (bf16_t)a.x; r[1] = (bf16_t)a.y; r[2] = (bf16_t)a.z; r[3] = (bf16_t)a.w;
    r[4] = (bf16_t)b.x; r[5] = (bf16_t)b.y; r[6] = (bf16_t)b.z; r[7] = (bf16_t)b.w;
    return r;
}

__global__ __launch_bounds__(256, 3)
void head_attn_kernel(const float* __restrict__ x,
                      const float* __restrict__ Wq,
                      const float* __restrict__ Wk,
                      const float* __restrict__ Wv,
                      float* __restrict__ out)
{
    __shared__ __align__(16) char smem[LDS_BYTES];
    const int tid  = threadIdx.x;
    const int w    = tid >> 6;
    const int lane = tid & 63;
    const int l15  = lane & 15;
    const int lg   = lane >> 4;
    const int t    = w * 16 + l15;          // lane's owned query/time row
    char* qscr = smem + QS_OFF + w * 2048;

    const size_t b0 = (size_t)blockIdx.x * NB;
    const float* xrow = x + b0 * 8192 + t * 128 + lg * 8;

    // W row bases for this lane (h = j*16 + l15; j>>2 selects Wq/Wk/Wv)
    const float* pw0 = Wq + l15 * 128;
    const float* pw1 = Wk + l15 * 128;
    const float* pw2 = Wv + l15 * 128;

    // ---- prefetch batch 0 x row (8 independent float4 loads) ----
    float4 xr0 = *(const float4*)(xrow +   0), xr1 = *(const float4*)(xrow +   4);
    float4 xr2 = *(const float4*)(xrow +  32), xr3 = *(const float4*)(xrow +  36);
    float4 xr4 = *(const float4*)(xrow +  64), xr5 = *(const float4*)(xrow +  68);
    float4 xr6 = *(const float4*)(xrow +  96), xr7 = *(const float4*)(xrow + 100);

    f32x4 oacc[4];

    #pragma unroll
    for (int i = 0; i < NB; ++i) {
        // convert current x to MFMA B-fragments
        bf16x8 xb[4];
        xb[0] = pack8(xr0, xr1); xb[1] = pack8(xr2, xr3);
        xb[2] = pack8(xr4, xr5); xb[3] = pack8(xr6, xr7);

        // issue next batch's x loads early (hide under QKV + attention)
        if (i + 1 < NB) {
            const float* xn = xrow + (size_t)(i + 1) * 8192;
            xr0 = *(const float4*)(xn +   0); xr1 = *(const float4*)(xn +   4);
            xr2 = *(const float4*)(xn +  32); xr3 = *(const float4*)(xn +  36);
            xr4 = *(const float4*)(xn +  64); xr5 = *(const float4*)(xn +  68);
            xr6 = *(const float4*)(xn +  96); xr7 = *(const float4*)(xn + 100);
        }

        // deferred out store of previous batch (overlaps this QKV phase)
        if (i > 0) {
            float* ob = out + (b0 + i - 1) * 4096 + t * 64 + lg * 4;
            #pragma unroll
            for (int ht = 0; ht < 4; ++ht)
                *reinterpret_cast<float4*>(ob + ht * 16) =
                    (float4){oacc[ht][0], oacc[ht][1], oacc[ht][2], oacc[ht][3]};
        }

        // ------------- QKV (swapped): D[h][t] = W[h][:] . x[t][:] ----------
        f32x4 acc[12];
        #pragma unroll
        for (int j = 0; j < 12; ++j) acc[j] = (f32x4){0.f, 0.f, 0.f, 0.f};

        #pragma unroll
        for (int ks = 0; ks < 4; ++ks) {
            #pragma unroll
            for (int g = 0; g < 3; ++g) {          // 3 groups of 4 j's
                float4 wa[4], wb[4];
                #pragma unroll
                for (int jj = 0; jj < 4; ++jj) {   // batch 8 loads
                    int j = g * 4 + jj;
                    const float* base = (j < 4) ? pw0 : (j < 8) ? pw1 : pw2;
                    const float* wp = base + (j & 3) * 2048 + ks * 32 + lg * 8;
                    wa[jj] = *(const float4*)(wp);
                    wb[jj] = *(const float4*)(wp + 4);
                }
                #pragma unroll
                for (int jj = 0; jj < 4; ++jj)
                    acc[g * 4 + jj] = __builtin_amdgcn_mfma_f32_16x16x32_bf16(
                        pack8(wa[jj], wb[jj]), xb[ks], acc[g * 4 + jj], 0, 0, 0);
            }
        }

        // q -> wave scratch [t_loc][h]; k -> K[s][h]; v -> VT[h][s]
        #pragma unroll
        for (int j = 0; j < 4; ++j) {
            bf16x4 pk;
            pk[0] = (bf16_t)acc[j][0]; pk[1] = (bf16_t)acc[j][1];
            pk[2] = (bf16_t)acc[j][2]; pk[3] = (bf16_t)acc[j][3];
            *reinterpret_cast<bf16x4*>(qscr + swz(l15 * 128 + (j * 16 + lg * 4) * 2, l15)) = pk;
        }
        #pragma unroll
        for (int j = 4; j < 8; ++j) {
            bf16x4 pk;
            pk[0] = (bf16_t)acc[j][0]; pk[1] = (bf16_t)acc[j][1];
            pk[2] = (bf16_t)acc[j][2]; pk[3] = (bf16_t)acc[j][3];
            *reinterpret_cast<bf16x4*>(smem + swz(K_OFF + t * 128 + ((j - 4) * 16 + lg * 4) * 2, t)) = pk;
        }
        #pragma unroll
        for (int j = 8; j < 12; ++j)
            #pragma unroll
            for (int r = 0; r < 4; ++r) {
                int h = (j - 8) * 16 + lg * 4 + r;
                *reinterpret_cast<bf16_t*>(smem + swz(VT_OFF + h * 128 + t * 2, h)) = (bf16_t)acc[j][r];
            }
        __syncthreads();

        // ------------- S^T = K . q^T : lane = col t, regs = s --------------
        f32x4 sacc[4];
        #pragma unroll
        for (int st = 0; st < 4; ++st) sacc[st] = (f32x4){0.f, 0.f, 0.f, 0.f};
        #pragma unroll
        for (int ks = 0; ks < 2; ++ks) {
            int h0 = ks * 32 + lg * 8;
            bf16x8 qf = *reinterpret_cast<const bf16x8*>(qscr + swz(l15 * 128 + h0 * 2, l15));
            #pragma unroll
            for (int st = 0; st < 4; ++st) {
                int s = st * 16 + l15;
                bf16x8 kf = *reinterpret_cast<const bf16x8*>(smem + swz(K_OFF + s * 128 + h0 * 2, s));
                sacc[st] = __builtin_amdgcn_mfma_f32_16x16x32_bf16(kf, qf, sacc[st], 0, 0, 0);
            }
        }

        // ------------- softmax: lane owns full row t (16 regs) -------------
        float p[4][4];
        float m = -1e30f;
        #pragma unroll
        for (int st = 0; st < 4; ++st)
            #pragma unroll
            for (int r = 0; r < 4; ++r) {
                int s = st * 16 + lg * 4 + r;
                float v = sacc[st][r] * 0.125f;
                v = (s <= t) ? v : -1e30f;     // causal
                p[st][r] = v;
                m = fmaxf(m, v);
            }
        m = fmaxf(m, __shfl_xor(m, 16));
        m = fmaxf(m, __shfl_xor(m, 32));
        float sum = 0.f;
        #pragma unroll
        for (int st = 0; st < 4; ++st)
            #pragma unroll
            for (int r = 0; r < 4; ++r) {
                float e = __expf(p[st][r] - m);
                p[st][r] = e;
                sum += e;
            }
        sum += __shfl_xor(sum, 16);
        sum += __shfl_xor(sum, 32);
        float inv = 1.0f / sum;
        #pragma unroll
        for (int st = 0; st < 4; ++st) {
            bf16x4 pk;
            pk[0] = (bf16_t)(p[st][0] * inv); pk[1] = (bf16_t)(p[st][1] * inv);
            pk[2] = (bf16_t)(p[st][2] * inv); pk[3] = (bf16_t)(p[st][3] * inv);
            *reinterpret_cast<bf16x4*>(qscr + swz(l15 * 128 + (st * 16 + lg * 4) * 2, l15)) = pk;
        }
        // wave-private scratch: same-wave write->read, in-order, no barrier

        // ------------- out^T = V^T . P^T (swapped): lane = col t -----------
        #pragma unroll
        for (int ht = 0; ht < 4; ++ht) oacc[ht] = (f32x4){0.f, 0.f, 0.f, 0.f};
        #pragma unroll
        for (int ks = 0; ks < 2; ++ks) {
            int s0 = ks * 32 + lg * 8;
            bf16x8 pf = *reinterpret_cast<const bf16x8*>(qscr + swz(l15 * 128 + s0 * 2, l15));
            #pragma unroll
            for (int ht = 0; ht < 4; ++ht) {
                int h = ht * 16 + l15;
                bf16x8 vf = *reinterpret_cast<const bf16x8*>(smem + swz(VT_OFF + h * 128 + s0 * 2, h));
                oacc[ht] = __builtin_amdgcn_mfma_f32_16x16x32_bf16(vf, pf, oacc[ht], 0, 0, 0);
            }
        }
        __syncthreads();   // protect K/VT/QS before next batch's QKV writes
    }

    // final batch's out store
    {
        float* ob = out + (b0 + NB - 1) * 4096 + t * 64 + lg * 4;
        #pragma unroll
        for (int ht = 0; ht < 4; ++ht)
            *reinterpret_cast<float4*>(ob + ht * 16) =
                (float4){oacc[ht][0], oacc[ht][1], oacc[ht][2], oacc[ht][3]};
    }
}

extern "C" void kernel_launch(void* const* d_in, const int* in_sizes, int n_in,
                              void* d_out, int out_size, void* d_ws, size_t ws_size,
                              hipStream_t stream) {
    const float* x  = (const float*)d_in[0];
    const float* Wq = (const float*)d_in[1];
    const float* Wk = (const float*)d_in[2];
    const float* Wv = (const float*)d_in[3];
    float* out = (float*)d_out;
    int B = in_sizes[0] / (64 * 128);   // 4096
    head_attn_kernel<<<B / NB, 256, 0, stream>>>(x, Wq, Wk, Wv, out);
}

// Round 6
// 81.315 us; speedup vs baseline: 11.3450x; 11.3450x over previous
//
#include <hip/hip_runtime.h>
#include <hip/hip_bf16.h>

// Single-head causal attention, B=4096, T=64, C=128, H=64.
// One block (4 waves) per batch. Wave w owns query rows [16w,16w+16).
// All matmuls bf16 MFMA 16x16x32, operand-swapped so q/k/P tiles land
// row-packed and out stores are float4.
// R5 post-mortem: NB=2 + cross-batch liveness demanded ~190 regs > 170 budget
// -> 2.4 GB spill traffic, 945us. This round: NB=1, batched W-frag loads
// (12 x 16B per k-step), bf16 W precomputed in ws. Peak pressure ~130 regs.

typedef __bf16 bf16_t;
typedef __bf16 bf16x8 __attribute__((ext_vector_type(8)));
typedef __bf16 bf16x4 __attribute__((ext_vector_type(4)));
typedef float  f32x4  __attribute__((ext_vector_type(4)));

#define K_OFF   0        // K [s][h]  64x64 bf16, rowstride 128 B, swizzled
#define VT_OFF  8192     // VT [h][s] 64x64 bf16
#define QS_OFF  16384    // per-wave scratch (q then P): w*2048, 16x64 bf16
#define LDS_BYTES 24576

__device__ __forceinline__ int swz(int off, int row) { return off ^ ((row & 7) << 4); }

__device__ __forceinline__ bf16x8 pack8(float4 a, float4 b) {
    bf16x8 r;
    r[0] = (bf16_t)a.x; r[1] = (bf16_t)a.y; r[2] = (bf16_t)a.z; r[3] = (bf16_t)a.w;
    r[4] = (bf16_t)b.x; r[5] = (bf16_t)b.y; r[6] = (bf16_t)b.z; r[7] = (bf16_t)b.w;
    return r;
}

// W bf16 in ws: w2[(ks*192 + h)*32 + c]  (ks-major; per-ks slice = 12 KB)
__global__ void wcvt_kernel(const float* __restrict__ Wq, const float* __restrict__ Wk,
                            const float* __restrict__ Wv, bf16_t* __restrict__ w2)
{
    int i   = blockIdx.x * 256 + threadIdx.x;   // 6144 threads, 4 elems each
    int ks  = i / 1536;
    int rem = i - ks * 1536;
    int h   = rem >> 3;
    int c4  = (rem & 7) * 4;
    const float* wr = (h < 64) ? Wq + h * 128 : (h < 128) ? Wk + (h - 64) * 128
                                                          : Wv + (h - 128) * 128;
    float4 v = *reinterpret_cast<const float4*>(wr + ks * 32 + c4);
    bf16x4 pk;
    pk[0] = (bf16_t)v.x; pk[1] = (bf16_t)v.y; pk[2] = (bf16_t)v.z; pk[3] = (bf16_t)v.w;
    *reinterpret_cast<bf16x4*>(w2 + (ks * 192 + h) * 32 + c4) = pk;
}

template<bool USE_WS>
__global__ __launch_bounds__(256, 3)
void head_attn_kernel(const float* __restrict__ x,
                      const float* __restrict__ Wq,
                      const float* __restrict__ Wk,
                      const float* __restrict__ Wv,
                      const bf16_t* __restrict__ w2,
                      float* __restrict__ out)
{
    __shared__ __align__(16) char smem[LDS_BYTES];
    const int b    = blockIdx.x;
    const int tid  = threadIdx.x;
    const int w    = tid >> 6;
    const int lane = tid & 63;
    const int l15  = lane & 15;
    const int lg   = lane >> 4;
    const int t    = w * 16 + l15;          // lane's owned query/time row
    char* qscr = smem + QS_OFF + w * 2048;

    // ---- 8 independent x float4 loads, issued up front ----
    const float* xrow = x + (size_t)b * 8192 + t * 128 + lg * 8;
    float4 xr0 = *(const float4*)(xrow +   0), xr1 = *(const float4*)(xrow +   4);
    float4 xr2 = *(const float4*)(xrow +  32), xr3 = *(const float4*)(xrow +  36);
    float4 xr4 = *(const float4*)(xrow +  64), xr5 = *(const float4*)(xrow +  68);
    float4 xr6 = *(const float4*)(xrow +  96), xr7 = *(const float4*)(xrow + 100);

    bf16x8 xb[4];
    xb[0] = pack8(xr0, xr1); xb[1] = pack8(xr2, xr3);
    xb[2] = pack8(xr4, xr5); xb[3] = pack8(xr6, xr7);

    // ------------- QKV (swapped): D[h][t] = W[h][:] . x[t][:] --------------
    // acc[j]: h-tile j (q: 0..3, k: 4..7, v: 8..11); lane = col t, regs = 4 h rows
    f32x4 acc[12];
    #pragma unroll
    for (int j = 0; j < 12; ++j) acc[j] = (f32x4){0.f, 0.f, 0.f, 0.f};

    if constexpr (USE_WS) {
        const bf16_t* wbase = w2 + l15 * 32 + lg * 8;
        #pragma unroll
        for (int ks = 0; ks < 4; ++ks) {
            bf16x8 wf[12];                       // 12 x 16B loads batched in flight
            #pragma unroll
            for (int j = 0; j < 12; ++j)
                wf[j] = *reinterpret_cast<const bf16x8*>(wbase + ks * 6144 + j * 512);
            #pragma unroll
            for (int j = 0; j < 12; ++j)
                acc[j] = __builtin_amdgcn_mfma_f32_16x16x32_bf16(wf[j], xb[ks], acc[j], 0, 0, 0);
        }
    } else {
        const float* pw0 = Wq + l15 * 128;
        const float* pw1 = Wk + l15 * 128;
        const float* pw2 = Wv + l15 * 128;
        #pragma unroll
        for (int ks = 0; ks < 4; ++ks) {
            #pragma unroll
            for (int g = 0; g < 3; ++g) {        // groups of 4 j's: 8 loads in flight
                float4 wa[4], wc[4];
                #pragma unroll
                for (int jj = 0; jj < 4; ++jj) {
                    int j = g * 4 + jj;
                    const float* base = (j < 4) ? pw0 : (j < 8) ? pw1 : pw2;
                    const float* wp = base + (j & 3) * 2048 + ks * 32 + lg * 8;
                    wa[jj] = *(const float4*)(wp);
                    wc[jj] = *(const float4*)(wp + 4);
                }
                #pragma unroll
                for (int jj = 0; jj < 4; ++jj)
                    acc[g * 4 + jj] = __builtin_amdgcn_mfma_f32_16x16x32_bf16(
                        pack8(wa[jj], wc[jj]), xb[ks], acc[g * 4 + jj], 0, 0, 0);
            }
        }
    }

    // q -> wave scratch [t_loc][h]; k -> K[s][h]; v -> VT[h][s]
    #pragma unroll
    for (int j = 0; j < 4; ++j) {
        bf16x4 pk;
        pk[0] = (bf16_t)acc[j][0]; pk[1] = (bf16_t)acc[j][1];
        pk[2] = (bf16_t)acc[j][2]; pk[3] = (bf16_t)acc[j][3];
        *reinterpret_cast<bf16x4*>(qscr + swz(l15 * 128 + (j * 16 + lg * 4) * 2, l15)) = pk;
    }
    #pragma unroll
    for (int j = 4; j < 8; ++j) {
        bf16x4 pk;
        pk[0] = (bf16_t)acc[j][0]; pk[1] = (bf16_t)acc[j][1];
        pk[2] = (bf16_t)acc[j][2]; pk[3] = (bf16_t)acc[j][3];
        *reinterpret_cast<bf16x4*>(smem + swz(K_OFF + t * 128 + ((j - 4) * 16 + lg * 4) * 2, t)) = pk;
    }
    #pragma unroll
    for (int j = 8; j < 12; ++j)
        #pragma unroll
        for (int r = 0; r < 4; ++r) {
            int h = (j - 8) * 16 + lg * 4 + r;
            *reinterpret_cast<bf16_t*>(smem + swz(VT_OFF + h * 128 + t * 2, h)) = (bf16_t)acc[j][r];
        }
    __syncthreads();

    // ------------- S^T = K . q^T : lane = col t, regs = s ------------------
    f32x4 sacc[4];
    #pragma unroll
    for (int st = 0; st < 4; ++st) sacc[st] = (f32x4){0.f, 0.f, 0.f, 0.f};
    #pragma unroll
    for (int ks = 0; ks < 2; ++ks) {
        int h0 = ks * 32 + lg * 8;
        bf16x8 qf = *reinterpret_cast<const bf16x8*>(qscr + swz(l15 * 128 + h0 * 2, l15));
        #pragma unroll
        for (int st = 0; st < 4; ++st) {
            int s = st * 16 + l15;
            bf16x8 kf = *reinterpret_cast<const bf16x8*>(smem + swz(K_OFF + s * 128 + h0 * 2, s));
            sacc[st] = __builtin_amdgcn_mfma_f32_16x16x32_bf16(kf, qf, sacc[st], 0, 0, 0);
        }
    }

    // ------------- softmax: lane owns full row t (16 regs) -----------------
    float p[4][4];
    float m = -1e30f;
    #pragma unroll
    for (int st = 0; st < 4; ++st)
        #pragma unroll
        for (int r = 0; r < 4; ++r) {
            int s = st * 16 + lg * 4 + r;
            float v = sacc[st][r] * 0.125f;
            v = (s <= t) ? v : -1e30f;     // causal
            p[st][r] = v;
            m = fmaxf(m, v);
        }
    m = fmaxf(m, __shfl_xor(m, 16));
    m = fmaxf(m, __shfl_xor(m, 32));
    float sum = 0.f;
    #pragma unroll
    for (int st = 0; st < 4; ++st)
        #pragma unroll
        for (int r = 0; r < 4; ++r) {
            float e = __expf(p[st][r] - m);
            p[st][r] = e;
            sum += e;
        }
    sum += __shfl_xor(sum, 16);
    sum += __shfl_xor(sum, 32);
    float inv = 1.0f / sum;
    #pragma unroll
    for (int st = 0; st < 4; ++st) {
        bf16x4 pk;
        pk[0] = (bf16_t)(p[st][0] * inv); pk[1] = (bf16_t)(p[st][1] * inv);
        pk[2] = (bf16_t)(p[st][2] * inv); pk[3] = (bf16_t)(p[st][3] * inv);
        *reinterpret_cast<bf16x4*>(qscr + swz(l15 * 128 + (st * 16 + lg * 4) * 2, l15)) = pk;
    }
    // wave-private scratch: same-wave write->read, in-order, no barrier

    // ------------- out^T = V^T . P^T (swapped): lane = col t ---------------
    f32x4 oacc[4];
    #pragma unroll
    for (int ht = 0; ht < 4; ++ht) oacc[ht] = (f32x4){0.f, 0.f, 0.f, 0.f};
    #pragma unroll
    for (int ks = 0; ks < 2; ++ks) {
        int s0 = ks * 32 + lg * 8;
        bf16x8 pf = *reinterpret_cast<const bf16x8*>(qscr + swz(l15 * 128 + s0 * 2, l15));
        #pragma unroll
        for (int ht = 0; ht < 4; ++ht) {
            int h = ht * 16 + l15;
            bf16x8 vf = *reinterpret_cast<const bf16x8*>(smem + swz(VT_OFF + h * 128 + s0 * 2, h));
            oacc[ht] = __builtin_amdgcn_mfma_f32_16x16x32_bf16(vf, pf, oacc[ht], 0, 0, 0);
        }
    }

    float* ob = out + (size_t)b * 4096 + t * 64 + lg * 4;
    #pragma unroll
    for (int ht = 0; ht < 4; ++ht)
        *reinterpret_cast<float4*>(ob + ht * 16) =
            (float4){oacc[ht][0], oacc[ht][1], oacc[ht][2], oacc[ht][3]};
}

extern "C" void kernel_launch(void* const* d_in, const int* in_sizes, int n_in,
                              void* d_out, int out_size, void* d_ws, size_t ws_size,
                              hipStream_t stream) {
    const float* x  = (const float*)d_in[0];
    const float* Wq = (const float*)d_in[1];
    const float* Wk = (const float*)d_in[2];
    const float* Wv = (const float*)d_in[3];
    float* out = (float*)d_out;
    int B = in_sizes[0] / (64 * 128);   // 4096
    if (ws_size >= 192 * 128 * sizeof(bf16_t) && d_ws != nullptr) {
        bf16_t* w2 = (bf16_t*)d_ws;
        wcvt_kernel<<<24, 256, 0, stream>>>(Wq, Wk, Wv, w2);
        head_attn_kernel<true><<<B, 256, 0, stream>>>(x, Wq, Wk, Wv, w2, out);
    } else {
        head_attn_kernel<false><<<B, 256, 0, stream>>>(x, Wq, Wk, Wv, nullptr, out);
    }
}